// Round 11
// baseline (154.447 us; speedup 1.0000x reference)
//
#include <hip/hip_runtime.h>
#include <hip/hip_bf16.h>

// ---------------------------------------------------------------------------
// FactorizedAttention fused (N=32, T=50, LQ=LK=64, E=128, H=8, d=16)
// SINGLE kernel, one block per (b,T) tile: QKV proj -> attention -> O proj.
// Round-11: prep kernel removed. Weights converted f32->bf16 inline per-ks
// (L2-hot, t3 compile-time so Wq*0.25 folds at phase 0 only); mask dtype
// detected per-block from the global first 4KB (deterministic, L2 broadcast).
// (512,3): VGPR cap ~85 (min-BLOCKS semantics, R9), spill-free precedent.
// LDS 32.9 KB: Xs[64][128] swz (X stage -> Oh), per-wave 2KB Sw time-shared
// Q-frag -> K-frag -> P staging. P,V,QK^T all in regs via 16x16x16 layout.
// out0: (N,T,LQ,E) f32 = 13107200 ; out1: attn (H,N,T,LQ,LK) f32 = 52428800
// ---------------------------------------------------------------------------

#define NBT 1600
#define OUT0_ELEMS 13107200L

typedef __attribute__((ext_vector_type(8))) short bf16x8;
typedef __attribute__((ext_vector_type(4))) short bf16x4;
typedef __attribute__((ext_vector_type(4))) float f32x4;
typedef __attribute__((ext_vector_type(4))) unsigned short u16x4;

__device__ __forceinline__ unsigned short f2b(float f) {
  union { float f; unsigned u; } v; v.f = f;
  unsigned r = v.u + 0x7FFFu + ((v.u >> 16) & 1u);
  return (unsigned short)(r >> 16);
}
__device__ __forceinline__ float b2f(unsigned short s) {
  union { unsigned u; float f; } v; v.u = ((unsigned)s) << 16;
  return v.f;
}
__device__ __forceinline__ bf16x4 pack4(f32x4 v) {
  bf16x4 r;
  r[0] = (short)f2b(v[0]); r[1] = (short)f2b(v[1]);
  r[2] = (short)f2b(v[2]); r[3] = (short)f2b(v[3]);
  return r;
}
__device__ __forceinline__ bf16x8 packw(float4 a, float4 b) {
  bf16x8 r;
  r[0] = (short)f2b(a.x); r[1] = (short)f2b(a.y);
  r[2] = (short)f2b(a.z); r[3] = (short)f2b(a.w);
  r[4] = (short)f2b(b.x); r[5] = (short)f2b(b.y);
  r[6] = (short)f2b(b.z); r[7] = (short)f2b(b.w);
  return r;
}

#if defined(__has_builtin)
#if __has_builtin(__builtin_amdgcn_mfma_f32_16x16x16bf16_1k)
#define HAVE_MFMA16_1K 1
#endif
#endif

__device__ __forceinline__ f32x4 mfma16(bf16x4 a, bf16x4 b, f32x4 c) {
#ifdef HAVE_MFMA16_1K
  return __builtin_amdgcn_mfma_f32_16x16x16bf16_1k(a, b, c, 0, 0, 0);
#else
  f32x4 d;
  asm volatile("v_mfma_f32_16x16x16_bf16 %0, %1, %2, %3\n\ts_nop 7\n\ts_nop 7"
               : "=v"(d)
               : "v"(a), "v"(b), "v"(c));
  return d;
#endif
}

// LDS swizzles (element = short).
// Xs logical [64][128]: idx = r*128 + (c ^ ((r&7)<<3)); mask<128 -> bijective;
// b128 reads recover contiguous c (mask bits 3..5 disjoint from offset 0..2).
__device__ __forceinline__ int xs_idx(int r, int c) {
  return r * 128 + (c ^ ((r & 7) << 3));
}
// Q/K logical [64][16] per wave: mask (l&3)<<2 in {0,4,8,12} < 16 -> bijective;
// b64 reads at d=4g recover d=4g..4g+3 (mask bits 2..3 disjoint from 0..1).
__device__ __forceinline__ int qk_idx(int l, int d) {
  return l * 16 + (d ^ ((l & 3) << 2));
}
// P staging, logical [16][64] per wave: mask (r&7)<<3 < 64 -> bijective;
// 4-short accesses keep 8-B alignment (mask is multiple of 8 shorts).
__device__ __forceinline__ int ps_idx(int r, int c) {
  return r * 64 + (c ^ ((r & 7) << 3));
}

// ---------------------------------------------------------------------------
// Fused kernel: 1600 blocks x 512 threads (8 waves; wave w = head w).
// ---------------------------------------------------------------------------
__global__ __launch_bounds__(512, 3) void fused_kernel(
    const float* __restrict__ q_in, const float* __restrict__ k_in,
    const float* __restrict__ v_in, const unsigned char* __restrict__ maskp,
    const float* __restrict__ Wq, const float* __restrict__ bq,
    const float* __restrict__ Wk, const float* __restrict__ bk,
    const float* __restrict__ Wv, const float* __restrict__ bv,
    const float* __restrict__ Wo, const float* __restrict__ bo,
    float* __restrict__ out0, float* __restrict__ attn_out) {
  __shared__ __align__(16) unsigned short Xs[64 * 128];   // 16384 B (swz; Oh)
  __shared__ __align__(16) unsigned short QKw[8 * 1024];  // 16384 B per-wave
  __shared__ float maskS[64];                             //   256 B
  __shared__ int sflags[2];                               //     8 B

  const int tid = threadIdx.x;
  const int w = tid >> 6;           // wave = head
  const int lane = tid & 63;
  const int ln = lane & 15, g = lane >> 4;
  const long bT = blockIdx.x;

  unsigned short* Sw = QKw + w * 1024;  // wave-private 2KB: Q -> K -> P stage

  const float* xsrc0 = q_in + bT * 8192;
  const float* xsrc1 = k_in + bT * 8192;
  const float* xsrc2 = v_in + bT * 8192;

  // issue first X tile loads immediately (overlap with mask detection)
  float4 xcur[4];
  #pragma unroll
  for (int it = 0; it < 4; ++it)
    xcur[it] = *(const float4*)(xsrc0 + it * 2048 + tid * 4);

  // ---- mask dtype detection from global first 4096 bytes (all blocks scan
  // the same window -> deterministic, L2-hot). mode 0=int32,1=bytes,2=f32
  if (tid < 2) sflags[tid] = 0;
  int bnz = 0, fcnt = 0;
  {
    #pragma unroll
    for (int i = 0; i < 8; ++i) {
      int idx = tid * 8 + i;
      if ((idx & 3) && maskp[idx]) bnz++;
    }
    const unsigned int* mw = (const unsigned int*)maskp;
    if (mw[tid * 2] == 0x3f800000u) fcnt++;
    if (mw[tid * 2 + 1] == 0x3f800000u) fcnt++;
  }
  __syncthreads();
  if (bnz) atomicAdd(&sflags[0], 1);
  if (fcnt) atomicAdd(&sflags[1], 1);
  __syncthreads();
  const int mode = sflags[1] ? 2 : (sflags[0] ? 1 : 0);

  // mask -> additive bias in LDS (first read in attention, many barriers away)
  if (tid < 64) {
    long midx = bT * 64 + tid;
    bool mk;
    if (mode == 0)      mk = ((const int*)maskp)[midx] != 0;
    else if (mode == 1) mk = maskp[midx] != 0;
    else                mk = ((const float*)maskp)[midx] != 0.0f;
    maskS[tid] = mk ? -INFINITY : 0.0f;
  }

  bf16x4 vk[4];         // V head tile, PV B-fragments (filled at t3==2)
  bf16x4 aK[4], bQ[4];  // QK^T fragments, read back as soon as staged

  // ---- QKV projections: Y[:,16w..16w+16) per wave; W converted inline ----
  #pragma unroll
  for (int t3 = 0; t3 < 3; ++t3) {
    // stage current tile -> Xs (bf16, swizzled)
    #pragma unroll
    for (int it = 0; it < 4; ++it) {
      int flat = it * 2048 + tid * 4;
      int r = flat >> 7, c = flat & 127;
      float4 xv = xcur[it];
      u16x4 pk;
      pk[0] = f2b(xv.x); pk[1] = f2b(xv.y);
      pk[2] = f2b(xv.z); pk[3] = f2b(xv.w);
      *(u16x4*)&Xs[xs_idx(r, c)] = pk;
    }
    // issue next tile's loads before the barrier (latency hides under MFMA)
    if (t3 < 2) {
      const float* nsrc = (t3 == 0) ? xsrc1 : xsrc2;
      #pragma unroll
      for (int it = 0; it < 4; ++it)
        xcur[it] = *(const float4*)(nsrc + it * 2048 + tid * 4);
    }
    __syncthreads();

    const float* Wsrc = (t3 == 0) ? Wq : (t3 == 1) ? Wk : Wv;
    const float* wrow = Wsrc + (w * 16 + ln) * 128 + 8 * g;
    const float* bias = (t3 == 0) ? bq : (t3 == 1) ? bk : bv;
    float bval = bias[w * 16 + ln] * ((t3 == 0) ? 0.25f : 1.0f);

    f32x4 acc[4] = {};
    #pragma unroll
    for (int ks = 0; ks < 4; ++ks) {
      float4 wa = *(const float4*)(wrow + ks * 32);
      float4 wb2 = *(const float4*)(wrow + ks * 32 + 4);
      if (t3 == 0) {  // compile-time: fold softmax scale into Wq (pow2 exact)
        wa.x *= 0.25f; wa.y *= 0.25f; wa.z *= 0.25f; wa.w *= 0.25f;
        wb2.x *= 0.25f; wb2.y *= 0.25f; wb2.z *= 0.25f; wb2.w *= 0.25f;
      }
      bf16x8 bwk = packw(wa, wb2);
      bf16x8 a[4];
      #pragma unroll
      for (int ms = 0; ms < 4; ++ms)
        a[ms] = *(const bf16x8*)&Xs[xs_idx(ms * 16 + ln, ks * 32 + 8 * g)];
      #pragma unroll
      for (int ms = 0; ms < 4; ++ms)
        acc[ms] = __builtin_amdgcn_mfma_f32_16x16x32_bf16(a[ms], bwk,
                                                          acc[ms], 0, 0, 0);
    }
    __syncthreads();  // all Xs reads done (after t3==2: Xs free -> Oh)

    // D: col=ln (head dim d), row=4g+r within each 16-row subtile
    #pragma unroll
    for (int ms = 0; ms < 4; ++ms) {
      if (t3 == 2) {
        f32x4 vb;
        #pragma unroll
        for (int r = 0; r < 4; ++r) vb[r] = acc[ms][r] + bval;
        vk[ms] = pack4(vb);  // V[t=16ms+4g+r][d=ln] -> PV B-frag, in-register
      } else {
        #pragma unroll
        for (int r = 0; r < 4; ++r) {
          int l = ms * 16 + 4 * g + r;
          Sw[qk_idx(l, ln)] = f2b(acc[ms][r] + bval);
        }
      }
    }
    // read fragments back before Sw is re-used (wave-local, DS in-order)
    if (t3 == 0) {
      #pragma unroll
      for (int i = 0; i < 4; ++i)
        bQ[i] = *(const bf16x4*)&Sw[qk_idx(i * 16 + ln, 4 * g)];
    } else if (t3 == 1) {
      #pragma unroll
      for (int i = 0; i < 4; ++i)
        aK[i] = *(const bf16x4*)&Sw[qk_idx(i * 16 + ln, 4 * g)];
    }
  }

  // ---- attention, per lsub (Sw now dead -> P staging) ----
  const long abase = ((long)w * NBT + bT) * 4096;
  #pragma unroll
  for (int lsub = 0; lsub < 4; ++lsub) {
    // QK^T: s4[t][r] = S[t=16t+4g+r][l=16lsub+ln]
    f32x4 s4[4];
    #pragma unroll
    for (int t = 0; t < 4; ++t) {
      f32x4 z = {};
      s4[t] = mfma16(aK[t], bQ[lsub], z);
    }
    // softmax over the 16 in-lane t values + cross-g shfl (mask from LDS)
    float m = -INFINITY;
    #pragma unroll
    for (int t = 0; t < 4; ++t) {
      f32x4 mvt = *(const f32x4*)&maskS[t * 16 + 4 * g];
      #pragma unroll
      for (int r = 0; r < 4; ++r) {
        float sv = s4[t][r] + mvt[r];
        s4[t][r] = sv;
        m = fmaxf(m, sv);
      }
    }
    m = fmaxf(m, __shfl_xor(m, 16, 64));
    m = fmaxf(m, __shfl_xor(m, 32, 64));
    float sum = 0.f;
    #pragma unroll
    for (int t = 0; t < 4; ++t)
      #pragma unroll
      for (int r = 0; r < 4; ++r) {
        float p = (m == -INFINITY) ? 0.f : __expf(s4[t][r] - m);
        s4[t][r] = p;
        sum += p;
      }
    sum += __shfl_xor(sum, 16, 64);
    sum += __shfl_xor(sum, 32, 64);
    float inv = (sum > 0.f) ? 1.f / sum : 0.f;

    // pack P -> bf16 fragments (PV A-operand AND staging source)
    bf16x4 pa4[4];
    #pragma unroll
    for (int t = 0; t < 4; ++t) {
      f32x4 ps;
      #pragma unroll
      for (int r = 0; r < 4; ++r) ps[r] = s4[t][r] * inv;
      pa4[t] = pack4(ps);
    }

    // stage q-rows 16lsub..16lsub+15 through Sw, then dense 1KB stores
    #pragma unroll
    for (int t = 0; t < 4; ++t)
      *(u16x4*)&Sw[ps_idx(ln, t * 16 + 4 * g)] = *(const u16x4*)&pa4[t];
    #pragma unroll
    for (int j = 0; j < 4; ++j) {
      int row = 4 * j + g;
      u16x4 pv = *(const u16x4*)&Sw[ps_idx(row, 4 * ln)];
      float4 o = make_float4(b2f(pv[0]), b2f(pv[1]), b2f(pv[2]), b2f(pv[3]));
      *(float4*)&attn_out[abase + (long)(lsub * 16 + row) * 64 + 4 * ln] = o;
    }

    // PV: O[l][d] = sum_t P[l][t] V[t][d]; write Oh (Xs alias) immediately
    f32x4 oacc = {};
    #pragma unroll
    for (int t = 0; t < 4; ++t) oacc = mfma16(pa4[t], vk[t], oacc);
    #pragma unroll
    for (int r = 0; r < 4; ++r)
      Xs[xs_idx(lsub * 16 + 4 * g + r, w * 16 + ln)] = f2b(oacc[r]);
  }

  __syncthreads();  // Oh (in Xs) complete (cross-wave read next)

  // ---- O projection: out0 = Oh @ Wo^T + bo (Wo converted inline) ----
  {
    const float* wrow = Wo + (w * 16 + ln) * 128 + 8 * g;
    float bov = bo[w * 16 + ln];

    f32x4 acc[4] = {};
    #pragma unroll
    for (int ks = 0; ks < 4; ++ks) {
      float4 wa = *(const float4*)(wrow + ks * 32);
      float4 wb2 = *(const float4*)(wrow + ks * 32 + 4);
      bf16x8 bwk = packw(wa, wb2);
      bf16x8 a[4];
      #pragma unroll
      for (int ms = 0; ms < 4; ++ms)
        a[ms] = *(const bf16x8*)&Xs[xs_idx(ms * 16 + ln, ks * 32 + 8 * g)];
      #pragma unroll
      for (int ms = 0; ms < 4; ++ms)
        acc[ms] = __builtin_amdgcn_mfma_f32_16x16x32_bf16(a[ms], bwk,
                                                          acc[ms], 0, 0, 0);
    }
    #pragma unroll
    for (int ms = 0; ms < 4; ++ms)
      #pragma unroll
      for (int r = 0; r < 4; ++r)
        out0[(bT * 64 + ms * 16 + 4 * g + r) * 128 + w * 16 + ln] =
            acc[ms][r] + bov;
  }
}

// ---------------------------------------------------------------------------
extern "C" void kernel_launch(void* const* d_in, const int* in_sizes, int n_in,
                              void* d_out, int out_size, void* d_ws,
                              size_t ws_size, hipStream_t stream) {
  (void)in_sizes; (void)n_in; (void)out_size; (void)d_ws; (void)ws_size;
  const float* query = (const float*)d_in[0];
  const float* key   = (const float*)d_in[1];
  const float* value = (const float*)d_in[2];
  const unsigned char* mask = (const unsigned char*)d_in[3];
  const float* Wq = (const float*)d_in[4];
  const float* bq = (const float*)d_in[5];
  const float* Wk = (const float*)d_in[6];
  const float* bk = (const float*)d_in[7];
  const float* Wv = (const float*)d_in[8];
  const float* bv = (const float*)d_in[9];
  const float* Wo = (const float*)d_in[10];
  const float* bo = (const float*)d_in[11];

  float* out0 = (float*)d_out;
  float* attn_out = out0 + OUT0_ELEMS;

  fused_kernel<<<NBT, 512, 0, stream>>>(query, key, value, mask,
                                        Wq, bq, Wk, bk, Wv, bv, Wo, bo,
                                        out0, attn_out);
}

// Round 14
// 106.534 us; speedup vs baseline: 1.4498x; 1.4498x over previous
//
#include <hip/hip_runtime.h>
#include <hip/hip_bf16.h>

// ---------------------------------------------------------------------------
// FactorizedAttention fused (N=32, T=50, LQ=LK=64, E=128, H=8, d=16)
// One block per (b,T) tile: QKV proj -> attention -> O proj.
// Round-14: NT stores reverted (broke post-timing determinism in R13 despite
// 91 us replay — graph-replay + nt cache semantics, not worth the risk).
// Instead: Xs DOUBLE-BUFFER halves barriers 8 -> 4. Phase buffers:
// t3=0->Xs0, t3=1->Xs1, t3=2->Xs0, Oh->Xs1. A wave reaches barrier N+1 only
// after its phase-N LDS reads completed, so re-staging a buffer two phases
// later is WAR-safe with ONE barrier per phase. LDS 49.2 KB -> 3 blocks/CU
// at (512,3) (VGPR cap ~85, min-BLOCKS semantics per R9; no spill).
// out0: (N,T,LQ,E) f32 = 13107200 ; out1: attn (H,N,T,LQ,LK) f32 = 52428800
// ---------------------------------------------------------------------------

#define NBT 1600
#define OUT0_ELEMS 13107200L

typedef __attribute__((ext_vector_type(8))) short bf16x8;
typedef __attribute__((ext_vector_type(4))) short bf16x4;
typedef __attribute__((ext_vector_type(4))) float f32x4;
typedef __attribute__((ext_vector_type(4))) unsigned short u16x4;

__device__ __forceinline__ unsigned short f2b(float f) {
  union { float f; unsigned u; } v; v.f = f;
  unsigned r = v.u + 0x7FFFu + ((v.u >> 16) & 1u);
  return (unsigned short)(r >> 16);
}
__device__ __forceinline__ float b2f(unsigned short s) {
  union { unsigned u; float f; } v; v.u = ((unsigned)s) << 16;
  return v.f;
}
__device__ __forceinline__ bf16x4 pack4(f32x4 v) {
  bf16x4 r;
  r[0] = (short)f2b(v[0]); r[1] = (short)f2b(v[1]);
  r[2] = (short)f2b(v[2]); r[3] = (short)f2b(v[3]);
  return r;
}

#if defined(__has_builtin)
#if __has_builtin(__builtin_amdgcn_mfma_f32_16x16x16bf16_1k)
#define HAVE_MFMA16_1K 1
#endif
#endif

__device__ __forceinline__ f32x4 mfma16(bf16x4 a, bf16x4 b, f32x4 c) {
#ifdef HAVE_MFMA16_1K
  return __builtin_amdgcn_mfma_f32_16x16x16bf16_1k(a, b, c, 0, 0, 0);
#else
  f32x4 d;
  asm volatile("v_mfma_f32_16x16x16_bf16 %0, %1, %2, %3\n\ts_nop 7\n\ts_nop 7"
               : "=v"(d)
               : "v"(a), "v"(b), "v"(c));
  return d;
#endif
}

// LDS swizzles (element = short).
// Xs logical [64][128]: idx = r*128 + (c ^ ((r&7)<<3)); mask<128 -> bijective;
// b128 reads recover contiguous c (mask bits 3..5 disjoint from offset 0..2).
__device__ __forceinline__ int xs_idx(int r, int c) {
  return r * 128 + (c ^ ((r & 7) << 3));
}
// Q/K logical [64][16] per wave: mask (l&3)<<2 in {0,4,8,12} < 16 -> bijective;
// b64 reads at d=4g recover d=4g..4g+3 (mask bits 2..3 disjoint from 0..1).
__device__ __forceinline__ int qk_idx(int l, int d) {
  return l * 16 + (d ^ ((l & 3) << 2));
}
// P staging, logical [16][64] per wave: mask (r&7)<<3 < 64 -> bijective;
// 4-short accesses keep 8-B alignment (mask is multiple of 8 shorts).
__device__ __forceinline__ int ps_idx(int r, int c) {
  return r * 64 + (c ^ ((r & 7) << 3));
}

// ---------------------------------------------------------------------------
// Merged prep: blocks 0..255 convert weights to bf16 (scale 0.25 folded into
// Wq — exact, pow2); block 256 classifies the mask dtype.
// mode 0 = int32, 1 = bytes, 2 = f32
// ---------------------------------------------------------------------------
__global__ void prep_kernel(const float* __restrict__ Wq,
                            const float* __restrict__ Wk,
                            const float* __restrict__ Wv,
                            const float* __restrict__ Wo,
                            const unsigned char* __restrict__ maskp,
                            unsigned short* __restrict__ wall,
                            int* __restrict__ flag) {
  int b = blockIdx.x;
  int t = threadIdx.x;
  if (b < 256) {
    int idx = b * 256 + t;  // 65536 total
    int m = idx >> 14, j = idx & 16383;
    const float* src = (m == 0) ? Wq : (m == 1) ? Wk : (m == 2) ? Wv : Wo;
    float s = (m == 0) ? 0.25f : 1.0f;
    wall[idx] = f2b(src[j] * s);
  } else {
    __shared__ int sb, sf;
    if (t == 0) { sb = 0; sf = 0; }
    __syncthreads();
    int bnz = 0, fcnt = 0;
    for (int i = t * 16; i < t * 16 + 16; ++i)
      if ((i & 3) && maskp[i]) bnz++;
    const unsigned int* w = (const unsigned int*)maskp;
    for (int i = t * 4; i < t * 4 + 4; ++i)
      if (w[i] == 0x3f800000u) fcnt++;
    if (bnz) atomicAdd(&sb, 1);
    if (fcnt) atomicAdd(&sf, 1);
    __syncthreads();
    if (t == 0) *flag = sf ? 2 : (sb ? 1 : 0);
  }
}

// ---------------------------------------------------------------------------
// Fused kernel: 1600 blocks x 512 threads (8 waves; wave w = head w).
// ---------------------------------------------------------------------------
__global__ __launch_bounds__(512, 3) void fused_kernel(
    const float* __restrict__ q_in, const float* __restrict__ k_in,
    const float* __restrict__ v_in, const unsigned char* __restrict__ maskp,
    const int* __restrict__ modeFlag, const unsigned short* __restrict__ wall,
    const float* __restrict__ bq, const float* __restrict__ bk,
    const float* __restrict__ bv, const float* __restrict__ bo,
    float* __restrict__ out0, float* __restrict__ attn_out) {
  __shared__ __align__(16) unsigned short Xs0[64 * 128];  // 16384 B (X; V; swz)
  __shared__ __align__(16) unsigned short Xs1[64 * 128];  // 16384 B (X; Oh)
  __shared__ __align__(16) unsigned short QKw[8 * 1024];  // 16384 B per-wave
  __shared__ float maskS[64];                             //   256 B

  const int tid = threadIdx.x;
  const int w = tid >> 6;           // wave = head
  const int lane = tid & 63;
  const int ln = lane & 15, g = lane >> 4;
  const long bT = blockIdx.x;

  unsigned short* Sw = QKw + w * 1024;  // wave-private 2KB: Q -> K -> P stage

  // mask -> additive bias in LDS (before barrier 1; read after barrier 3)
  if (tid < 64) {
    int mode = *modeFlag;
    long midx = bT * 64 + tid;
    bool mk;
    if (mode == 0)      mk = ((const int*)maskp)[midx] != 0;
    else if (mode == 1) mk = maskp[midx] != 0;
    else                mk = ((const float*)maskp)[midx] != 0.0f;
    maskS[tid] = mk ? -INFINITY : 0.0f;
  }

  const float* xsrc0 = q_in + bT * 8192;
  const float* xsrc1 = k_in + bT * 8192;
  const float* xsrc2 = v_in + bT * 8192;

  // 1-deep pipeline: only the current tile lives in registers (16 VGPR)
  float4 xcur[4];
  #pragma unroll
  for (int it = 0; it < 4; ++it)
    xcur[it] = *(const float4*)(xsrc0 + it * 2048 + tid * 4);

  bf16x4 vk[4];         // V head tile, PV B-fragments (filled at t3==2)
  bf16x4 aK[4], bQ[4];  // QK^T fragments, read back as soon as staged

  // ---- QKV projections: Y[:,16w..16w+16) per wave; ONE barrier per phase.
  // Buffers: t3=0 -> Xs0, t3=1 -> Xs1, t3=2 -> Xs0 (WAR-safe: every wave's
  // t3=0 reads of Xs0 finished before it reached barrier 2).
  #pragma unroll
  for (int t3 = 0; t3 < 3; ++t3) {
    unsigned short* Xb = (t3 == 1) ? Xs1 : Xs0;
    // stage current tile -> Xb (bf16, swizzled); overlaps other waves' reads
    // of the OTHER buffer (no conflict).
    #pragma unroll
    for (int it = 0; it < 4; ++it) {
      int flat = it * 2048 + tid * 4;
      int r = flat >> 7, c = flat & 127;
      float4 xv = xcur[it];
      u16x4 pk;
      pk[0] = f2b(xv.x); pk[1] = f2b(xv.y);
      pk[2] = f2b(xv.z); pk[3] = f2b(xv.w);
      *(u16x4*)&Xb[xs_idx(r, c)] = pk;
    }
    // issue next tile's loads before the barrier (latency hides under MFMA)
    if (t3 < 2) {
      const float* nsrc = (t3 == 0) ? xsrc1 : xsrc2;
      #pragma unroll
      for (int it = 0; it < 4; ++it)
        xcur[it] = *(const float4*)(nsrc + it * 2048 + tid * 4);
    }
    __syncthreads();  // barrier t3+1: Xb staged (and prior-buffer reads done)

    const unsigned short* wb = wall + t3 * 16384 + (w * 16 + ln) * 128 + 8 * g;
    const float* bias = (t3 == 0) ? bq : (t3 == 1) ? bk : bv;
    float bval = bias[w * 16 + ln] * ((t3 == 0) ? 0.25f : 1.0f);

    f32x4 acc[4] = {};
    #pragma unroll
    for (int ks = 0; ks < 4; ++ks) {
      bf16x8 bwk = *(const bf16x8*)(wb + ks * 32);  // per-ks: 4 VGPR live
      bf16x8 a[4];
      #pragma unroll
      for (int ms = 0; ms < 4; ++ms)
        a[ms] = *(const bf16x8*)&Xb[xs_idx(ms * 16 + ln, ks * 32 + 8 * g)];
      #pragma unroll
      for (int ms = 0; ms < 4; ++ms)
        acc[ms] = __builtin_amdgcn_mfma_f32_16x16x32_bf16(a[ms], bwk,
                                                          acc[ms], 0, 0, 0);
    }
    // NO reads-done barrier: folded into the next phase's staging barrier.

    // D: col=ln (head dim d), row=4g+r within each 16-row subtile
    #pragma unroll
    for (int ms = 0; ms < 4; ++ms) {
      if (t3 == 2) {
        f32x4 vb;
        #pragma unroll
        for (int r = 0; r < 4; ++r) vb[r] = acc[ms][r] + bval;
        vk[ms] = pack4(vb);  // V[t=16ms+4g+r][d=ln] -> PV B-frag, in-register
      } else {
        #pragma unroll
        for (int r = 0; r < 4; ++r) {
          int l = ms * 16 + 4 * g + r;
          Sw[qk_idx(l, ln)] = f2b(acc[ms][r] + bval);
        }
      }
    }
    // read fragments back before Sw is re-used (wave-local, DS in-order)
    if (t3 == 0) {
      #pragma unroll
      for (int i = 0; i < 4; ++i)
        bQ[i] = *(const bf16x4*)&Sw[qk_idx(i * 16 + ln, 4 * g)];
    } else if (t3 == 1) {
      #pragma unroll
      for (int i = 0; i < 4; ++i)
        aK[i] = *(const bf16x4*)&Sw[qk_idx(i * 16 + ln, 4 * g)];
    }
  }

  // ---- attention, per lsub. Oh goes into Xs1 (its t3=1 reads finished
  // before every wave reached barrier 3 -> WAR-safe without a new barrier).
  const long abase = ((long)w * NBT + bT) * 4096;
  #pragma unroll
  for (int lsub = 0; lsub < 4; ++lsub) {
    // QK^T: s4[t][r] = S[t=16t+4g+r][l=16lsub+ln]
    f32x4 s4[4];
    #pragma unroll
    for (int t = 0; t < 4; ++t) {
      f32x4 z = {};
      s4[t] = mfma16(aK[t], bQ[lsub], z);
    }
    // softmax over the 16 in-lane t values + cross-g shfl (mask from LDS)
    float m = -INFINITY;
    #pragma unroll
    for (int t = 0; t < 4; ++t) {
      f32x4 mvt = *(const f32x4*)&maskS[t * 16 + 4 * g];
      #pragma unroll
      for (int r = 0; r < 4; ++r) {
        float sv = s4[t][r] + mvt[r];
        s4[t][r] = sv;
        m = fmaxf(m, sv);
      }
    }
    m = fmaxf(m, __shfl_xor(m, 16, 64));
    m = fmaxf(m, __shfl_xor(m, 32, 64));
    float sum = 0.f;
    #pragma unroll
    for (int t = 0; t < 4; ++t)
      #pragma unroll
      for (int r = 0; r < 4; ++r) {
        float p = (m == -INFINITY) ? 0.f : __expf(s4[t][r] - m);
        s4[t][r] = p;
        sum += p;
      }
    sum += __shfl_xor(sum, 16, 64);
    sum += __shfl_xor(sum, 32, 64);
    float inv = (sum > 0.f) ? 1.f / sum : 0.f;

    // pack P -> bf16 fragments (PV A-operand AND staging source)
    bf16x4 pa4[4];
    #pragma unroll
    for (int t = 0; t < 4; ++t) {
      f32x4 ps;
      #pragma unroll
      for (int r = 0; r < 4; ++r) ps[r] = s4[t][r] * inv;
      pa4[t] = pack4(ps);
    }

    // stage q-rows 16lsub..16lsub+15 through Sw, then dense 1KB stores
    #pragma unroll
    for (int t = 0; t < 4; ++t)
      *(u16x4*)&Sw[ps_idx(ln, t * 16 + 4 * g)] = *(const u16x4*)&pa4[t];
    #pragma unroll
    for (int j = 0; j < 4; ++j) {
      int row = 4 * j + g;
      u16x4 pv = *(const u16x4*)&Sw[ps_idx(row, 4 * ln)];
      f32x4 o;
      o[0] = b2f(pv[0]); o[1] = b2f(pv[1]);
      o[2] = b2f(pv[2]); o[3] = b2f(pv[3]);
      *(f32x4*)&attn_out[abase + (long)(lsub * 16 + row) * 64 + 4 * ln] = o;
    }

    // PV: O[l][d] = sum_t P[l][t] V[t][d]; write Oh (Xs1 alias) immediately
    f32x4 oacc = {};
    #pragma unroll
    for (int t = 0; t < 4; ++t) oacc = mfma16(pa4[t], vk[t], oacc);
    #pragma unroll
    for (int r = 0; r < 4; ++r)
      Xs1[xs_idx(lsub * 16 + 4 * g + r, w * 16 + ln)] = f2b(oacc[r]);
  }

  __syncthreads();  // barrier 4: Oh (in Xs1) complete (cross-wave read next)

  // ---- O projection: out0 = Oh @ Wo^T + bo ----
  {
    const unsigned short* wo = wall + 3 * 16384 + (w * 16 + ln) * 128 + 8 * g;
    float bov = bo[w * 16 + ln];

    f32x4 acc[4] = {};
    #pragma unroll
    for (int ks = 0; ks < 4; ++ks) {
      bf16x8 bwk = *(const bf16x8*)(wo + ks * 32);
      bf16x8 a[4];
      #pragma unroll
      for (int ms = 0; ms < 4; ++ms)
        a[ms] = *(const bf16x8*)&Xs1[xs_idx(ms * 16 + ln, ks * 32 + 8 * g)];
      #pragma unroll
      for (int ms = 0; ms < 4; ++ms)
        acc[ms] = __builtin_amdgcn_mfma_f32_16x16x32_bf16(a[ms], bwk,
                                                          acc[ms], 0, 0, 0);
    }
    #pragma unroll
    for (int ms = 0; ms < 4; ++ms)
      #pragma unroll
      for (int r = 0; r < 4; ++r)
        out0[(bT * 64 + ms * 16 + 4 * g + r) * 128 + w * 16 + ln] =
            acc[ms][r] + bov;
  }
}

// ---------------------------------------------------------------------------
extern "C" void kernel_launch(void* const* d_in, const int* in_sizes, int n_in,
                              void* d_out, int out_size, void* d_ws,
                              size_t ws_size, hipStream_t stream) {
  (void)in_sizes; (void)n_in; (void)out_size; (void)ws_size;
  const float* query = (const float*)d_in[0];
  const float* key   = (const float*)d_in[1];
  const float* value = (const float*)d_in[2];
  const unsigned char* mask = (const unsigned char*)d_in[3];
  const float* Wq = (const float*)d_in[4];
  const float* bq = (const float*)d_in[5];
  const float* Wk = (const float*)d_in[6];
  const float* bk = (const float*)d_in[7];
  const float* Wv = (const float*)d_in[8];
  const float* bv = (const float*)d_in[9];
  const float* Wo = (const float*)d_in[10];
  const float* bo = (const float*)d_in[11];

  float* out0 = (float*)d_out;
  float* attn_out = out0 + OUT0_ELEMS;

  char* ws = (char*)d_ws;
  int* flag = (int*)ws;
  unsigned short* wall = (unsigned short*)(ws + 256);  // 65536 bf16

  prep_kernel<<<257, 256, 0, stream>>>(Wq, Wk, Wv, Wo, mask, wall, flag);
  fused_kernel<<<NBT, 512, 0, stream>>>(query, key, value, mask, flag, wall,
                                        bq, bk, bv, bo, out0, attn_out);
}